// Round 1
// baseline (51.328 us; speedup 1.0000x reference)
//
#include <hip/hip_runtime.h>

// Problem constants (from reference)
constexpr int N = 2;
constexpr int C = 20;
constexpr int H = 64;
constexpr int W = 2048;          // power of two -> wrap via & (W-1)
constexpr int HW = H * W;

__global__ __launch_bounds__(256)
void lcl_xyz_kernel(const float* __restrict__ xyz,
                    const float* __restrict__ softmax,
                    const int* __restrict__ mask,
                    float* __restrict__ out) {
    int idx = blockIdx.x * blockDim.x + threadIdx.x;   // (n*H + h)*W + w
    int w = idx & (W - 1);
    int nh = idx >> 11;          // / W
    int h = nh & (H - 1);
    int n = nh >> 6;             // / H

    const float* xb = xyz + (size_t)(n * 3 + 0) * HW;
    const float* yb = xyz + (size_t)(n * 3 + 1) * HW;
    const float* zb = xyz + (size_t)(n * 3 + 2) * HW;
    const int*   mb = mask + (size_t)n * HW;

    const int center = h * W + w;
    const float cx = xb[center];
    const float cy = yb[center];
    const float cz = zb[center];

    // Precompute the 25 gaussian*mask*valid weights (class-independent).
    float wgt[25];
    #pragma unroll
    for (int i = 0; i < 5; ++i) {
        int hh = h + i - 2;
        bool valid = (hh >= 0) && (hh < H);
        int hc = min(max(hh, 0), H - 1);
        #pragma unroll
        for (int j = 0; j < 5; ++j) {
            int ww = (w + j - 2) & (W - 1);
            int off = hc * W + ww;
            float dx = xb[off] - cx;
            float dy = yb[off] - cy;
            float dz = zb[off] - cz;
            float d2 = dx * dx + dy * dy + dz * dz;
            float g = __expf(-0.5f * d2);          // GAUSS_DEN = 2*sigma^2 = 2
            g = valid ? g : 0.0f;
            g = mb[off] ? g : 0.0f;                // neighbor's mask folds into sm
            wgt[i * 5 + j] = g;
        }
    }

    const float* smb = softmax + (size_t)n * C * HW;
    float*       ob  = out     + (size_t)n * C * HW;

    for (int c = 0; c < C; ++c) {
        const float* sc = smb + (size_t)c * HW;
        float acc = 0.0f;
        #pragma unroll
        for (int i = 0; i < 5; ++i) {
            int hh = h + i - 2;
            int hc = min(max(hh, 0), H - 1);
            const float* srow = sc + hc * W;
            #pragma unroll
            for (int j = 0; j < 5; ++j) {
                int ww = (w + j - 2) & (W - 1);
                acc = fmaf(wgt[i * 5 + j], srow[ww], acc);
            }
        }
        ob[(size_t)c * HW + center] = acc;
    }
}

extern "C" void kernel_launch(void* const* d_in, const int* in_sizes, int n_in,
                              void* d_out, int out_size, void* d_ws, size_t ws_size,
                              hipStream_t stream) {
    const float* xyz     = (const float*)d_in[0];
    const float* softmax = (const float*)d_in[1];
    const int*   mask    = (const int*)d_in[2];
    float*       out     = (float*)d_out;

    const int total = N * H * W;                  // 262144 threads, 1 per (n,h,w)
    const int block = 256;
    const int grid  = total / block;              // 1024 blocks
    lcl_xyz_kernel<<<grid, block, 0, stream>>>(xyz, softmax, mask, out);
}

// Round 2
// 28.619 us; speedup vs baseline: 1.7935x; 1.7935x over previous
//
#include <hip/hip_runtime.h>

// Problem constants (from reference)
constexpr int N = 2;
constexpr int C = 20;
constexpr int H = 64;
constexpr int W = 2048;          // power of two -> wrap via & (W-1)
constexpr int HW = H * W;

constexpr int TILE  = 256;       // outputs (w positions) per block
constexpr int LCOLS = TILE + 8;  // staged cols: w0-4 .. w0+259 (aligned f4 span)
constexpr int F4    = LCOLS / 4; // 66 float4 groups per row
constexpr int ITEMS = 5 * F4;    // 330 float4 stage items per channel

__global__ __launch_bounds__(256)
void lcl_xyz_kernel(const float* __restrict__ xyz,
                    const float* __restrict__ softmax,
                    const int* __restrict__ mask,
                    float* __restrict__ out) {
    __shared__ float sx[5][LCOLS];
    __shared__ float sy[5][LCOLS];
    __shared__ float sz[5][LCOLS];
    __shared__ int   sk[5][LCOLS];   // mask
    __shared__ float sp[5][LCOLS];   // per-class softmax slab

    const int t  = threadIdx.x;
    const int bw = blockIdx.x & 7;          // 8 w-tiles per row
    const int h  = (blockIdx.x >> 3) & 63;
    const int n  = blockIdx.x >> 9;
    const int w0 = bw * TILE;

    const float* xb = xyz + (size_t)(n * 3 + 0) * HW;
    const float* yb = xyz + (size_t)(n * 3 + 1) * HW;
    const float* zb = xyz + (size_t)(n * 3 + 2) * HW;
    const int*   mb = mask + (size_t)n * HW;

    // ---- Stage xyz + mask: 5 rows x 264 cols, float4-vectorized ----
    for (int it = t; it < ITEMS; it += 256) {
        int r  = it / F4;
        int k  = it - r * F4;
        int hc = min(max(h - 2 + r, 0), H - 1);
        int col = (w0 - 4 + 4 * k) & (W - 1);   // 4-aligned, wrap-safe
        int rowoff = hc * W + col;
        *(float4*)&sx[r][4 * k] = *(const float4*)(xb + rowoff);
        *(float4*)&sy[r][4 * k] = *(const float4*)(yb + rowoff);
        *(float4*)&sz[r][4 * k] = *(const float4*)(zb + rowoff);
        *(int4*)  &sk[r][4 * k] = *(const int4*)  (mb + rowoff);
    }
    __syncthreads();

    // ---- Compute 25 gaussian*mask*valid weights (class-independent) ----
    const int ci = t + 4;                    // LDS col of this thread's center
    const float cx = sx[2][ci];              // row r=2 is h itself (always valid)
    const float cy = sy[2][ci];
    const float cz = sz[2][ci];

    float wgt[25];
    #pragma unroll
    for (int r = 0; r < 5; ++r) {
        bool valid = (unsigned)(h - 2 + r) < (unsigned)H;
        #pragma unroll
        for (int j = 0; j < 5; ++j) {
            int cc = t + 2 + j;              // ci + (j-2)
            float dx = sx[r][cc] - cx;
            float dy = sy[r][cc] - cy;
            float dz = sz[r][cc] - cz;
            float d2 = dx * dx + dy * dy + dz * dz;
            float g  = __expf(-0.5f * d2);   // GAUSS_DEN = 2*sigma^2 = 2
            g = (valid && sk[r][cc]) ? g : 0.0f;
            wgt[r * 5 + j] = g;
        }
    }

    // ---- Per class: cooperative stage softmax slab, then 25-tap FMA ----
    const float* smb = softmax + (size_t)n * C * HW;
    float*       op  = out + (size_t)n * C * HW + (size_t)h * W + w0 + t;

    for (int c = 0; c < C; ++c) {
        __syncthreads();                     // previous slab fully consumed
        const float* sc = smb + (size_t)c * HW;
        for (int it = t; it < ITEMS; it += 256) {
            int r  = it / F4;
            int k  = it - r * F4;
            int hc = min(max(h - 2 + r, 0), H - 1);
            int col = (w0 - 4 + 4 * k) & (W - 1);
            *(float4*)&sp[r][4 * k] = *(const float4*)(sc + hc * W + col);
        }
        __syncthreads();

        float acc = 0.0f;
        #pragma unroll
        for (int r = 0; r < 5; ++r) {
            #pragma unroll
            for (int j = 0; j < 5; ++j) {
                acc = fmaf(wgt[r * 5 + j], sp[r][t + 2 + j], acc);
            }
        }
        op[(size_t)c * HW] = acc;
    }
}

extern "C" void kernel_launch(void* const* d_in, const int* in_sizes, int n_in,
                              void* d_out, int out_size, void* d_ws, size_t ws_size,
                              hipStream_t stream) {
    const float* xyz     = (const float*)d_in[0];
    const float* softmax = (const float*)d_in[1];
    const int*   mask    = (const int*)d_in[2];
    float*       out     = (float*)d_out;

    const int grid = N * H * (W / TILE);     // 2*64*8 = 1024 blocks
    lcl_xyz_kernel<<<grid, 256, 0, stream>>>(xyz, softmax, mask, out);
}